// Round 4
// baseline (475.740 us; speedup 1.0000x reference)
//
#include <hip/hip_runtime.h>
#include <hip/hip_bf16.h>
#include <hip/hip_fp16.h>

// Problem constants (match reference)
static constexpr int CH     = 128;   // IN_CH == HID
static constexpr int NCLS   = 32;
static constexpr int NGRAPH = 256;

// Bucketed CSR build: buckets are 256-node ranges (bucket = dst >> 8).
static constexpr int BSHIFT = 8;
static constexpr int BW     = 1 << BSHIFT;   // 256 nodes per bucket
static constexpr int MAXB   = 512;

typedef _Float16 half8 __attribute__((ext_vector_type(8)));
typedef _Float16 half4 __attribute__((ext_vector_type(4)));
typedef float    f32x4 __attribute__((ext_vector_type(4)));
typedef float    f32x2 __attribute__((ext_vector_type(2)));

// fp8 (OCP e4m3) gather buffer, stored channel-split: xs[2][(N+1)][64].
// Each aggregation pass touches one 6.4MB half -> much higher L2 hit rate
// than the 12.8MB row-major layout (the R3 bottleneck was L2-miss/L3 random
// bandwidth ~2.4 TB/s, not CU-side issue or MLP).
static constexpr float FP8_SCALE = 64.0f;
static constexpr float FP8_INV   = 1.0f / 64.0f;

__device__ __forceinline__ float dec8_lo(unsigned char u) {
  f32x2 t = __builtin_amdgcn_cvt_pk_f32_fp8((int)u, false);
  return t[0];
}
__device__ __forceinline__ unsigned char enc8(float v) {
  return (unsigned char)(__builtin_amdgcn_cvt_pk_fp8_f32(v, v, 0, false) & 0xFF);
}

// ---------------------------------------------------------------------------
// 1) init: block 0 sets bucket cursors to b*CAP and zeroes the two fp8 pad
//    rows (row N of each channel half; CSR padding points here so padded
//    gathers add +0.0). blocks 1..128: W1,W2 -> fp16 transpose.
// ---------------------------------------------------------------------------
__global__ __launch_bounds__(256) void k_init_wt(
    int* __restrict__ gcur, int CAP, int NBUCK,
    int* __restrict__ xzero, int zstride_words,
    const float* __restrict__ W1, const float* __restrict__ W2,
    _Float16* __restrict__ WhT1, _Float16* __restrict__ WhT2) {
  int t = threadIdx.x;
  if (blockIdx.x == 0) {
    for (int i = t; i < NBUCK; i += 256) gcur[i] = i * CAP;
    if (t < 16) {                       // 64B zero row per channel half
      xzero[t] = 0;
      xzero[zstride_words + t] = 0;
    }
    return;
  }
  int i = (blockIdx.x - 1) * 256 + t;       // 0..32767
  const float* W = (i < CH * CH) ? W1 : W2;
  _Float16* T   = (i < CH * CH) ? WhT1 : WhT2;
  int j = i & (CH * CH - 1);
  int k = j >> 7, n = j & 127;
  T[n * CH + k] = (_Float16)W[j];
}

// ---------------------------------------------------------------------------
// 2) scatter packed edges into over-allocated bucket regions.
//    pack = (dstlo << 17) | src   (dstlo < 256 -> 8 bits; src < 2^17)
// ---------------------------------------------------------------------------
__global__ __launch_bounds__(1024) void k_scatter(
    const int* __restrict__ src, const int* __restrict__ dst,
    int* __restrict__ gcur, int* __restrict__ ebuf, int E) {
  __shared__ int bcnt[MAXB];
  __shared__ int bbase[MAXB];
  int t = threadIdx.x;
  if (t < MAXB) bcnt[t] = 0;
  __syncthreads();
  int base = blockIdx.x * 8192;
  int s_[8], d_[8], r_[8];
  #pragma unroll
  for (int j = 0; j < 8; ++j) {
    int i = base + j * 1024 + t;
    if (i < E) {
      s_[j] = src[i];
      d_[j] = dst[i];
      r_[j] = atomicAdd(&bcnt[d_[j] >> BSHIFT], 1);
    }
  }
  __syncthreads();
  if (t < MAXB && bcnt[t]) bbase[t] = atomicAdd(&gcur[t], bcnt[t]);
  __syncthreads();
  #pragma unroll
  for (int j = 0; j < 8; ++j) {
    int i = base + j * 1024 + t;
    if (i < E) {
      int b = d_[j] >> BSHIFT;
      int p = ((d_[j] & (BW - 1)) << 17) | s_[j];
      ebuf[bbase[b] + r_[j]] = p;
    }
  }
}

// ---------------------------------------------------------------------------
// 3) per-bucket CSR build (packed edges, gapped CAP regions).
//    Per-node regions are 4-entry aligned; slots [deg, pdeg) are filled with
//    NPAD (= N, the zero row) so k_agg can read blind int4 chunks.
// ---------------------------------------------------------------------------
__global__ __launch_bounds__(1024) void k_build(
    const int* __restrict__ ebuf, const int* __restrict__ gcur,
    int* __restrict__ offs, int* __restrict__ oend,
    float* __restrict__ dinv, int* __restrict__ csr, int N, int CAP) {
  __shared__ int sdeg[BW];
  __shared__ int sscan[BW];
  int b = blockIdx.x;
  int t = threadIdx.x;
  int lo = b << BSHIFT;
  int e0 = b * CAP;
  int e1 = gcur[b];                  // b*CAP + bucket count after scatter

  if (t < BW) sdeg[t] = 0;
  __syncthreads();
  for (int e = e0 + t; e < e1; e += 1024)
    atomicAdd(&sdeg[ebuf[e] >> 17], 1);
  __syncthreads();
  if (t < BW) sscan[t] = (sdeg[t] + 3) & ~3;     // padded degree
  __syncthreads();
  for (int st = 1; st < BW; st <<= 1) {
    int v = (t < BW && t >= st) ? sscan[t - st] : 0;
    __syncthreads();
    if (t < BW) sscan[t] += v;
    __syncthreads();
  }
  if (t < BW) {
    int deg  = sdeg[t];
    int pdeg = (deg + 3) & ~3;
    int ex = b * CAP + sscan[t] - pdeg;          // 4-aligned (CAP%4==0)
    int n = lo + t;
    if (n < N) {
      offs[n] = ex;
      oend[n] = ex + deg;
      dinv[n] = 1.0f / sqrtf((float)(deg + 1));
      for (int q = deg; q < pdeg; ++q) csr[ex + q] = N;   // zero-row pad
    }
    sscan[t] = ex;                                // fill cursor
  }
  __syncthreads();
  for (int e = e0 + t; e < e1; e += 1024) {
    int p = ebuf[e];
    int pos = atomicAdd(&sscan[p >> 17], 1);
    csr[pos] = p & 0x1FFFF;
  }
}

// ---------------------------------------------------------------------------
// MFMA GEMM: 64-row tiles, 4 waves x 16 rows, K=128 single shot, epilogue
// scales by dinv*64 -> fp8 e4m3 into the CHANNEL-SPLIT layout
// xs[ch>>6][(row)][ch&63].
// ---------------------------------------------------------------------------
__device__ __forceinline__ void stage_w(const _Float16* __restrict__ WhT,
                                        _Float16 (*Ws)[136], int tid) {
  #pragma unroll
  for (int l = 0; l < 8; ++l) {
    int idx = tid + l * 256;            // 0..2047 half8 chunks
    int n = idx >> 4, k8 = (idx & 15) << 3;
    *(half8*)&Ws[n][k8] = *(const half8*)(WhT + n * CH + k8);
  }
}

__device__ __forceinline__ void gemm_core64(
    const _Float16 (*As)[136], const _Float16 (*Ws)[136],
    const float* __restrict__ dinv, unsigned char* __restrict__ C,
    int row0, int M, int tid) {
  int lane = tid & 63, wave = tid >> 6;
  int quad = lane >> 4, sub = lane & 15;
  int m0 = wave * 16;
  size_t NP1 = (size_t)M + 1;          // rows per channel half (incl pad row)

  f32x4 acc[8];
  #pragma unroll
  for (int j = 0; j < 8; ++j) acc[j] = (f32x4){0.f, 0.f, 0.f, 0.f};

  #pragma unroll
  for (int kc = 0; kc < 4; ++kc) {
    int ko = kc * 32 + quad * 8;
    half8 a = *(const half8*)&As[m0 + sub][ko];
    #pragma unroll
    for (int nt = 0; nt < 8; ++nt) {
      half8 b = *(const half8*)&Ws[nt * 16 + sub][ko];
      acc[nt] = __builtin_amdgcn_mfma_f32_16x16x32_f16(a, b, acc[nt], 0, 0, 0);
    }
  }
  #pragma unroll
  for (int r = 0; r < 4; ++r) {
    int row = row0 + m0 + quad * 4 + r;
    if (row < M) {
      float d = dinv[row] * FP8_SCALE;
      #pragma unroll
      for (int nt = 0; nt < 8; ++nt) {
        int ch = nt * 16 + sub;
        size_t cidx = ((size_t)(ch >> 6) * NP1 + row) * 64 + (ch & 63);
        C[cidx] = enc8(acc[nt][r] * d);
      }
    }
  }
}

// A input fp32 (layer 1: x), packed half4 LDS stores
__global__ __launch_bounds__(256) void k_gemm_f32(
    const float* __restrict__ A, const _Float16* __restrict__ WhT,
    const float* __restrict__ dinv, unsigned char* __restrict__ C, int M) {
  __shared__ _Float16 As[64][136];
  __shared__ _Float16 Ws[128][136];
  int tid = threadIdx.x;
  int row0 = blockIdx.x * 64;
  #pragma unroll
  for (int l = 0; l < 8; ++l) {
    int idx = tid + l * 256;
    int r = idx >> 5, c4 = (idx & 31) << 2;
    int rr = row0 + r; if (rr >= M) rr = M - 1;
    float4 v = *(const float4*)(A + (size_t)rr * CH + c4);
    half4 hv = { (_Float16)v.x, (_Float16)v.y, (_Float16)v.z, (_Float16)v.w };
    *(half4*)&As[r][c4] = hv;
  }
  stage_w(WhT, Ws, tid);
  __syncthreads();
  gemm_core64(As, Ws, dinv, C, row0, M, tid);
}

// A input fp16 (layer 2: h)
__global__ __launch_bounds__(256) void k_gemm_f16(
    const _Float16* __restrict__ A, const _Float16* __restrict__ WhT,
    const float* __restrict__ dinv, unsigned char* __restrict__ C, int M) {
  __shared__ _Float16 As[64][136];
  __shared__ _Float16 Ws[128][136];
  int tid = threadIdx.x;
  int row0 = blockIdx.x * 64;
  #pragma unroll
  for (int l = 0; l < 4; ++l) {
    int idx = tid + l * 256;
    int r = idx >> 4, c8 = (idx & 15) << 3;
    int rr = row0 + r; if (rr >= M) rr = M - 1;
    *(half8*)&As[r][c8] = *(const half8*)(A + (size_t)rr * CH + c8);
  }
  stage_w(WhT, Ws, tid);
  __syncthreads();
  gemm_core64(As, Ws, dinv, C, row0, M, tid);
}

// ---------------------------------------------------------------------------
// Aggregation (pull, CSR), one CHANNEL PASS per dispatch: xsp points at one
// 6.4MB half (rows of 64B, 1 byte/lane/edge). Two nodes per wave in
// lockstep, 2 chunks each (16 byte-gathers in flight), CSR prefetched one
// iteration ahead (bounded by csr over-allocation). outp is pre-offset by
// 64*pass; out row stride is CH (=128) halves.
// ---------------------------------------------------------------------------
__global__ __launch_bounds__(256) void k_agg(
    const unsigned char* __restrict__ xsp, const int* __restrict__ csr,
    const int* __restrict__ offs, const int* __restrict__ oend,
    const float* __restrict__ dinv, const float* __restrict__ biasp,
    __half* __restrict__ outp, int N) {
  int wid0  = blockIdx.x * 4 + (threadIdx.x >> 6);
  int lane  = threadIdx.x & 63;
  int wstep = gridDim.x * 4;
  float bb = biasp[lane];

  auto g = [&](int s) -> unsigned char {
    return xsp[((unsigned int)s << 6) | (unsigned int)lane];
  };

  for (int wid = wid0; wid * 2 < N; wid += wstep) {
    int nA = wid * 2, nB = nA + 1;
    bool hasB = (nB < N);

    int eA = offs[nA];
    int cA = (oend[nA] - eA + 3) >> 2;                 // chunk count
    int eB = hasB ? offs[nB] : eA;
    int cB = hasB ? ((oend[nB] - eB + 3) >> 2) : 0;

    float aA0 = dec8_lo(g(nA)), aA1 = 0.f;
    float aB0 = 0.f, aB1 = 0.f;
    if (hasB) aB0 = dec8_lo(g(nB));

    // ---- lockstep main: 16 byte-gathers in flight, csr prefetched ahead
    if (cA >= 2 && cB >= 2) {
      int4 ca0 = *(const int4*)(csr + eA);
      int4 ca1 = *(const int4*)(csr + eA + 4);
      int4 cb0 = *(const int4*)(csr + eB);
      int4 cb1 = *(const int4*)(csr + eB + 4);
      do {
        unsigned char uA0 = g(ca0.x), uA1 = g(ca0.y), uA2 = g(ca0.z), uA3 = g(ca0.w);
        unsigned char uA4 = g(ca1.x), uA5 = g(ca1.y), uA6 = g(ca1.z), uA7 = g(ca1.w);
        unsigned char uB0 = g(cb0.x), uB1 = g(cb0.y), uB2 = g(cb0.z), uB3 = g(cb0.w);
        unsigned char uB4 = g(cb1.x), uB5 = g(cb1.y), uB6 = g(cb1.z), uB7 = g(cb1.w);
        eA += 8; eB += 8; cA -= 2; cB -= 2;
        // prefetch next chunks (unconditional; bounded by csr over-allocation)
        int4 na0 = *(const int4*)(csr + eA);
        int4 na1 = *(const int4*)(csr + eA + 4);
        int4 nb0 = *(const int4*)(csr + eB);
        int4 nb1 = *(const int4*)(csr + eB + 4);
        aA0 += dec8_lo(uA0); aA1 += dec8_lo(uA1);
        aA0 += dec8_lo(uA2); aA1 += dec8_lo(uA3);
        aA0 += dec8_lo(uA4); aA1 += dec8_lo(uA5);
        aA0 += dec8_lo(uA6); aA1 += dec8_lo(uA7);
        aB0 += dec8_lo(uB0); aB1 += dec8_lo(uB1);
        aB0 += dec8_lo(uB2); aB1 += dec8_lo(uB3);
        aB0 += dec8_lo(uB4); aB1 += dec8_lo(uB5);
        aB0 += dec8_lo(uB6); aB1 += dec8_lo(uB7);
        ca0 = na0; ca1 = na1; cb0 = nb0; cb1 = nb1;
      } while (cA >= 2 && cB >= 2);
    }

    // ---- per-node drain: 2-chunk (8 gathers) then 1-chunk (4 gathers)
    auto drain = [&](int e, int c, float& a0, float& a1) {
      while (c >= 2) {
        int4 q0 = *(const int4*)(csr + e);
        int4 q1 = *(const int4*)(csr + e + 4);
        unsigned char u0 = g(q0.x), u1 = g(q0.y), u2 = g(q0.z), u3 = g(q0.w);
        unsigned char u4 = g(q1.x), u5 = g(q1.y), u6 = g(q1.z), u7 = g(q1.w);
        a0 += dec8_lo(u0); a1 += dec8_lo(u1); a0 += dec8_lo(u2); a1 += dec8_lo(u3);
        a0 += dec8_lo(u4); a1 += dec8_lo(u5); a0 += dec8_lo(u6); a1 += dec8_lo(u7);
        e += 8; c -= 2;
      }
      if (c > 0) {
        int4 q0 = *(const int4*)(csr + e);
        unsigned char u0 = g(q0.x), u1 = g(q0.y), u2 = g(q0.z), u3 = g(q0.w);
        a0 += dec8_lo(u0); a1 += dec8_lo(u1); a0 += dec8_lo(u2); a1 += dec8_lo(u3);
      }
    };
    drain(eA, cA, aA0, aA1);
    if (hasB) drain(eB, cB, aB0, aB1);

    {
      float dn = dinv[nA] * FP8_INV;
      float r = fmaf(aA0 + aA1, dn, bb);
      outp[(size_t)nA * CH + lane] = __float2half(fmaxf(r, 0.f));
    }
    if (hasB) {
      float dn = dinv[nB] * FP8_INV;
      float r = fmaf(aB0 + aB1, dn, bb);
      outp[(size_t)nB * CH + lane] = __float2half(fmaxf(r, 0.f));
    }
  }
}

// ---------------------------------------------------------------------------
// Pool + graph boundaries (batch sorted)
// ---------------------------------------------------------------------------
__global__ __launch_bounds__(128) void k_pool(
    const __half* __restrict__ h, const int* __restrict__ batch,
    float* __restrict__ gsum, int* __restrict__ gstart,
    int* __restrict__ gend, int N) {
  int ch = threadIdx.x;
  int n0 = blockIdx.x * 128;
  int n1 = n0 + 128; if (n1 > N) n1 = N;
  if (n0 >= N) return;
  for (int n = n0 + ch; n < n1; n += 128) {
    int g = batch[n];
    if (n == 0 || batch[n - 1] != g) gstart[g] = n;
    if (n == N - 1 || batch[n + 1] != g) gend[g] = n + 1;
  }
  float acc = 0.f;
  int curg = batch[n0];
  for (int n = n0; n < n1; ++n) {
    int g = batch[n];
    if (g != curg) {
      atomicAdd(&gsum[curg * CH + ch], acc);
      acc = 0.f; curg = g;
    }
    acc += __half2float(h[(size_t)n * CH + ch]);
  }
  atomicAdd(&gsum[curg * CH + ch], acc);
}

// ---------------------------------------------------------------------------
// FC
// ---------------------------------------------------------------------------
__global__ __launch_bounds__(64) void k_fc(
    const float* __restrict__ gsum, const int* __restrict__ gstart,
    const int* __restrict__ gend, const float* __restrict__ Wfc,
    const float* __restrict__ bfc, float* __restrict__ outp) {
  int g = blockIdx.x;
  int j = threadIdx.x;
  if (j >= NCLS) return;
  int cnt = gend[g] - gstart[g];
  float invc = 1.0f / fmaxf((float)cnt, 1.0f);
  float acc = 0.0f;
  for (int c = 0; c < CH; ++c)
    acc = fmaf(gsum[g * CH + c], Wfc[c * NCLS + j], acc);
  outp[g * NCLS + j] = fmaf(acc, invc, bfc[j]);
}

// ---------------------------------------------------------------------------
extern "C" void kernel_launch(void* const* d_in, const int* in_sizes, int n_in,
                              void* d_out, int out_size, void* d_ws, size_t ws_size,
                              hipStream_t stream) {
  const float* x    = (const float*)d_in[0];
  const int*   ei   = (const int*)d_in[1];
  const int*   batch= (const int*)d_in[2];
  const float* W1   = (const float*)d_in[3];
  const float* b1   = (const float*)d_in[4];
  const float* W2   = (const float*)d_in[5];
  const float* b2   = (const float*)d_in[6];
  const float* Wfc  = (const float*)d_in[7];
  const float* bfc  = (const float*)d_in[8];
  float* outp = (float*)d_out;

  const int N = in_sizes[0] / CH;       // 100000
  const int E = in_sizes[1] / 2;        // 3200000
  const int* src = ei;
  const int* dst = ei + E;
  const int NBUCK = (N + BW - 1) >> BSHIFT;   // 391
  // Over-allocated bucket capacity: mean + ~14 sigma + 4-align padding room.
  int CAP = (E / NBUCK) + (E / NBUCK) / 8 + 1280;
  CAP = (CAP + 3) & ~3;                       // keep per-bucket base 4-aligned

  // Workspace carve (256B aligned). First three buffers zeroed by ONE memset.
  char* w = (char*)d_ws;
  size_t o = 0;
  auto carve = [&](size_t bytes) -> void* {
    o = (o + 255) & ~(size_t)255;
    void* p = w + o;
    o += bytes;
    return p;
  };
  float*    gsum   = (float*)   carve((size_t)NGRAPH * CH * 4);  // zeroed
  int*      gstart = (int*)     carve((size_t)NGRAPH * 4);       // zeroed
  int*      gend   = (int*)     carve((size_t)NGRAPH * 4);       // zeroed
  size_t zbytes = o;
  int*      offs   = (int*)     carve((size_t)N * 4);
  int*      oendb  = (int*)     carve((size_t)N * 4);
  int*      gcur   = (int*)     carve(MAXB * 4);
  int*      csr    = (int*)     carve((size_t)NBUCK * CAP * 4);
  float*    dinv   = (float*)   carve((size_t)N * 4);
  _Float16* WhT1   = (_Float16*)carve((size_t)CH * CH * 2);
  _Float16* WhT2   = (_Float16*)carve((size_t)CH * CH * 2);
  // channel-split fp8 gather buffer: [2][(N+1)][64] (pad row per half)
  unsigned char* xsbuf = (unsigned char*)carve((size_t)2 * (N + 1) * 64);
  __half*   hbuf   = (__half*)  carve((size_t)N * CH * 2);            // fp16 h
  (void)ws_size;

  const size_t HALF = (size_t)(N + 1) * 64;   // bytes per channel half

  // ebuf (packed edges, gapped) aliases hbuf: NBUCK*CAP*4 ~ 16.4MB <= 25.6MB
  int* ebuf = (int*)hbuf;

  (void)hipMemsetAsync(gsum, 0, zbytes, stream);

  const int GB64 = (N + 63) / 64;       // 1563
  const int GB   = (N + 127) / 128;
  // k_agg: grid-stride, 2 nodes/wave, 4 waves/block; 2048 blocks ~ 8192 waves
  int AB = (N + 7) / 8;
  if (AB > 2048) AB = 2048;

  k_init_wt<<<129, 256, 0, stream>>>(gcur, CAP, NBUCK,
                                     (int*)(xsbuf + (size_t)N * 64),
                                     (int)(HALF / 4),
                                     W1, W2, WhT1, WhT2);
  k_scatter<<<(E + 8191) / 8192, 1024, 0, stream>>>(src, dst, gcur, ebuf, E);
  k_build  <<<NBUCK, 1024, 0, stream>>>(ebuf, gcur, offs, oendb, dinv, csr, N, CAP);

  // Layer 1: xs = fp8((x@W1)*dinv*64) ; h = fp16(relu(agg(xs)*dinv/64 + b1))
  k_gemm_f32<<<GB64, 256, 0, stream>>>(x, WhT1, dinv, xsbuf, N);
  k_agg<<<AB, 256, 0, stream>>>(xsbuf,        csr, offs, oendb, dinv, b1,      hbuf,      N);
  k_agg<<<AB, 256, 0, stream>>>(xsbuf + HALF, csr, offs, oendb, dinv, b1 + 64, hbuf + 64, N);
  // Layer 2
  k_gemm_f16<<<GB64, 256, 0, stream>>>((const _Float16*)hbuf, WhT2, dinv, xsbuf, N);
  k_agg<<<AB, 256, 0, stream>>>(xsbuf,        csr, offs, oendb, dinv, b2,      hbuf,      N);
  k_agg<<<AB, 256, 0, stream>>>(xsbuf + HALF, csr, offs, oendb, dinv, b2 + 64, hbuf + 64, N);

  // Pool (+ boundaries) + FC
  k_pool<<<GB, 128, 0, stream>>>(hbuf, batch, gsum, gstart, gend, N);
  k_fc<<<NGRAPH, 64, 0, stream>>>(gsum, gstart, gend, Wfc, bfc, outp);
  (void)out_size; (void)n_in;
}

// Round 5
// 394.955 us; speedup vs baseline: 1.2045x; 1.2045x over previous
//
#include <hip/hip_runtime.h>
#include <hip/hip_bf16.h>
#include <hip/hip_fp16.h>

// Problem constants (match reference)
static constexpr int CH     = 128;   // IN_CH == HID
static constexpr int NCLS   = 32;
static constexpr int NGRAPH = 256;

// Bucketed CSR build: buckets are 256-node ranges (bucket = dst >> 8).
static constexpr int BSHIFT = 8;
static constexpr int BW     = 1 << BSHIFT;   // 256 nodes per bucket
static constexpr int MAXB   = 512;

typedef _Float16 half8 __attribute__((ext_vector_type(8)));
typedef _Float16 half4 __attribute__((ext_vector_type(4)));
typedef float    f32x4 __attribute__((ext_vector_type(4)));
typedef float    f32x2 __attribute__((ext_vector_type(2)));

// fp8 (OCP e4m3) gather buffer, row-major [N+1][128] (row N = zero pad row).
// R1-R4 established the agg wall is ~49k wave-VMEM-instructions/us
// (~11 cy/instr), invariant in bytes and in-flight depth. R5 restructures to
// 8 edges per memory instruction (lane (e,c) loads 16B chunk c of edge e).
static constexpr float FP8_SCALE = 64.0f;
static constexpr float FP8_INV   = 1.0f / 64.0f;

__device__ __forceinline__ unsigned char enc8(float v) {
  return (unsigned char)(__builtin_amdgcn_cvt_pk_fp8_f32(v, v, 0, false) & 0xFF);
}

// ---------------------------------------------------------------------------
// 1) init: block 0 sets bucket cursors to b*CAP and zeroes the fp8 pad row.
//    blocks 1..128: W1,W2 -> fp16 transpose.
// ---------------------------------------------------------------------------
__global__ __launch_bounds__(256) void k_init_wt(
    int* __restrict__ gcur, int CAP, int NBUCK, int* __restrict__ xzero,
    const float* __restrict__ W1, const float* __restrict__ W2,
    _Float16* __restrict__ WhT1, _Float16* __restrict__ WhT2) {
  int t = threadIdx.x;
  if (blockIdx.x == 0) {
    for (int i = t; i < NBUCK; i += 256) gcur[i] = i * CAP;
    if (t < 32) xzero[t] = 0;              // 128B zero row
    return;
  }
  int i = (blockIdx.x - 1) * 256 + t;       // 0..32767
  const float* W = (i < CH * CH) ? W1 : W2;
  _Float16* T   = (i < CH * CH) ? WhT1 : WhT2;
  int j = i & (CH * CH - 1);
  int k = j >> 7, n = j & 127;
  T[n * CH + k] = (_Float16)W[j];
}

// ---------------------------------------------------------------------------
// 2) scatter packed edges into over-allocated bucket regions.
//    pack = (dstlo << 17) | src   (dstlo < 256 -> 8 bits; src < 2^17)
// ---------------------------------------------------------------------------
__global__ __launch_bounds__(1024) void k_scatter(
    const int* __restrict__ src, const int* __restrict__ dst,
    int* __restrict__ gcur, int* __restrict__ ebuf, int E) {
  __shared__ int bcnt[MAXB];
  __shared__ int bbase[MAXB];
  int t = threadIdx.x;
  if (t < MAXB) bcnt[t] = 0;
  __syncthreads();
  int base = blockIdx.x * 8192;
  int s_[8], d_[8], r_[8];
  #pragma unroll
  for (int j = 0; j < 8; ++j) {
    int i = base + j * 1024 + t;
    if (i < E) {
      s_[j] = src[i];
      d_[j] = dst[i];
      r_[j] = atomicAdd(&bcnt[d_[j] >> BSHIFT], 1);
    }
  }
  __syncthreads();
  if (t < MAXB && bcnt[t]) bbase[t] = atomicAdd(&gcur[t], bcnt[t]);
  __syncthreads();
  #pragma unroll
  for (int j = 0; j < 8; ++j) {
    int i = base + j * 1024 + t;
    if (i < E) {
      int b = d_[j] >> BSHIFT;
      int p = ((d_[j] & (BW - 1)) << 17) | s_[j];
      ebuf[bbase[b] + r_[j]] = p;
    }
  }
}

// ---------------------------------------------------------------------------
// 3) per-bucket CSR build (packed edges, gapped CAP regions).
//    Per-node regions are 8-entry aligned: [edges][self-loop][pad->N].
//    k_agg reads blind 8-slot groups (zero row N makes pads +0.0; self row
//    contributes xw[n]*dinv[n], giving the correct dinv^2 self term).
// ---------------------------------------------------------------------------
__global__ __launch_bounds__(1024) void k_build(
    const int* __restrict__ ebuf, const int* __restrict__ gcur,
    int* __restrict__ offs, int* __restrict__ oend,
    float* __restrict__ dinv, int* __restrict__ csr, int N, int CAP) {
  __shared__ int sdeg[BW];
  __shared__ int sscan[BW];
  int b = blockIdx.x;
  int t = threadIdx.x;
  int lo = b << BSHIFT;
  int e0 = b * CAP;
  int e1 = gcur[b];                  // b*CAP + bucket count after scatter

  if (t < BW) sdeg[t] = 0;
  __syncthreads();
  for (int e = e0 + t; e < e1; e += 1024)
    atomicAdd(&sdeg[ebuf[e] >> 17], 1);
  __syncthreads();
  if (t < BW) sscan[t] = (sdeg[t] + 8) & ~7;     // deg + self, padded to 8
  __syncthreads();
  for (int st = 1; st < BW; st <<= 1) {
    int v = (t < BW && t >= st) ? sscan[t - st] : 0;
    __syncthreads();
    if (t < BW) sscan[t] += v;
    __syncthreads();
  }
  if (t < BW) {
    int deg  = sdeg[t];
    int pdeg = (deg + 8) & ~7;
    int ex = b * CAP + sscan[t] - pdeg;          // 8-aligned (CAP%8==0)
    int n = lo + t;
    if (n < N) {
      offs[n] = ex;
      oend[n] = ex + pdeg;
      dinv[n] = 1.0f / sqrtf((float)(deg + 1));
      csr[ex + deg] = n;                          // self-loop entry
      for (int q = deg + 1; q < pdeg; ++q) csr[ex + q] = N;  // zero-row pad
    }
    sscan[t] = ex;                                // fill cursor
  }
  __syncthreads();
  for (int e = e0 + t; e < e1; e += 1024) {
    int p = ebuf[e];
    int pos = atomicAdd(&sscan[p >> 17], 1);
    csr[pos] = p & 0x1FFFF;
  }
}

// ---------------------------------------------------------------------------
// MFMA GEMM: 64-row tiles, 4 waves x 16 rows, K=128 single shot, epilogue
// scales by dinv*64 -> fp8 e4m3 row-major [row][ch].
// ---------------------------------------------------------------------------
__device__ __forceinline__ void stage_w(const _Float16* __restrict__ WhT,
                                        _Float16 (*Ws)[136], int tid) {
  #pragma unroll
  for (int l = 0; l < 8; ++l) {
    int idx = tid + l * 256;            // 0..2047 half8 chunks
    int n = idx >> 4, k8 = (idx & 15) << 3;
    *(half8*)&Ws[n][k8] = *(const half8*)(WhT + n * CH + k8);
  }
}

__device__ __forceinline__ void gemm_core64(
    const _Float16 (*As)[136], const _Float16 (*Ws)[136],
    const float* __restrict__ dinv, unsigned char* __restrict__ C,
    int row0, int M, int tid) {
  int lane = tid & 63, wave = tid >> 6;
  int quad = lane >> 4, sub = lane & 15;
  int m0 = wave * 16;

  f32x4 acc[8];
  #pragma unroll
  for (int j = 0; j < 8; ++j) acc[j] = (f32x4){0.f, 0.f, 0.f, 0.f};

  #pragma unroll
  for (int kc = 0; kc < 4; ++kc) {
    int ko = kc * 32 + quad * 8;
    half8 a = *(const half8*)&As[m0 + sub][ko];
    #pragma unroll
    for (int nt = 0; nt < 8; ++nt) {
      half8 b = *(const half8*)&Ws[nt * 16 + sub][ko];
      acc[nt] = __builtin_amdgcn_mfma_f32_16x16x32_f16(a, b, acc[nt], 0, 0, 0);
    }
  }
  #pragma unroll
  for (int r = 0; r < 4; ++r) {
    int row = row0 + m0 + quad * 4 + r;
    if (row < M) {
      float d = dinv[row] * FP8_SCALE;
      #pragma unroll
      for (int nt = 0; nt < 8; ++nt)
        C[(size_t)row * CH + nt * 16 + sub] = enc8(acc[nt][r] * d);
    }
  }
}

// A input fp32 (layer 1: x), packed half4 LDS stores
__global__ __launch_bounds__(256) void k_gemm_f32(
    const float* __restrict__ A, const _Float16* __restrict__ WhT,
    const float* __restrict__ dinv, unsigned char* __restrict__ C, int M) {
  __shared__ _Float16 As[64][136];
  __shared__ _Float16 Ws[128][136];
  int tid = threadIdx.x;
  int row0 = blockIdx.x * 64;
  #pragma unroll
  for (int l = 0; l < 8; ++l) {
    int idx = tid + l * 256;
    int r = idx >> 5, c4 = (idx & 31) << 2;
    int rr = row0 + r; if (rr >= M) rr = M - 1;
    float4 v = *(const float4*)(A + (size_t)rr * CH + c4);
    half4 hv = { (_Float16)v.x, (_Float16)v.y, (_Float16)v.z, (_Float16)v.w };
    *(half4*)&As[r][c4] = hv;
  }
  stage_w(WhT, Ws, tid);
  __syncthreads();
  gemm_core64(As, Ws, dinv, C, row0, M, tid);
}

// A input fp16 (layer 2: h)
__global__ __launch_bounds__(256) void k_gemm_f16(
    const _Float16* __restrict__ A, const _Float16* __restrict__ WhT,
    const float* __restrict__ dinv, unsigned char* __restrict__ C, int M) {
  __shared__ _Float16 As[64][136];
  __shared__ _Float16 Ws[128][136];
  int tid = threadIdx.x;
  int row0 = blockIdx.x * 64;
  #pragma unroll
  for (int l = 0; l < 4; ++l) {
    int idx = tid + l * 256;
    int r = idx >> 4, c8 = (idx & 15) << 3;
    int rr = row0 + r; if (rr >= M) rr = M - 1;
    *(half8*)&As[r][c8] = *(const half8*)(A + (size_t)rr * CH + c8);
  }
  stage_w(WhT, Ws, tid);
  __syncthreads();
  gemm_core64(As, Ws, dinv, C, row0, M, tid);
}

// ---------------------------------------------------------------------------
// Aggregation (pull, CSR), TRANSPOSED GATHER: one node per wave.
// lane = e*8 + c  (e = edge slot 0..7, c = 16B chunk 0..7 of the 128B row).
// One uint4 load fetches 8 full edge rows per wave instruction (8x fewer
// VMEM instructions than row-per-instruction). Blind 8-slot groups (CSR is
// padded with self-loop + zero-row entries). Per-lane acc = 16 channels as
// f32x2[8]; 3-stage shfl_xor butterfly (masks 8/16/32) reduces across e;
// lanes e==0 write the 128-half output row.
// ---------------------------------------------------------------------------
__global__ __launch_bounds__(256) void k_agg(
    const uint4* __restrict__ xs4, const int* __restrict__ csr,
    const int* __restrict__ offs, const int* __restrict__ oend,
    const float* __restrict__ dinv, const float* __restrict__ bias,
    __half* __restrict__ out, int N) {
  int lane  = threadIdx.x & 63;
  int w0    = blockIdx.x * 4 + (threadIdx.x >> 6);
  int wstep = gridDim.x * 4;
  int e = lane >> 3, c = lane & 7;

  // bias chunk for this lane (channels 16c..16c+15), constant across nodes
  float4 bb0 = *(const float4*)(bias + c * 16);
  float4 bb1 = *(const float4*)(bias + c * 16 + 4);
  float4 bb2 = *(const float4*)(bias + c * 16 + 8);
  float4 bb3 = *(const float4*)(bias + c * 16 + 12);

  for (int n = w0; n < N; n += wstep) {
    int base = offs[n];
    int ng = (oend[n] - base) >> 3;       // padded group count (>=1)

    f32x2 a[8];
    #pragma unroll
    for (int j = 0; j < 8; ++j) a[j] = (f32x2){0.f, 0.f};

    auto acc8 = [&](uint4 q) {
      a[0] += __builtin_amdgcn_cvt_pk_f32_fp8((int)q.x, false);
      a[1] += __builtin_amdgcn_cvt_pk_f32_fp8((int)q.x, true);
      a[2] += __builtin_amdgcn_cvt_pk_f32_fp8((int)q.y, false);
      a[3] += __builtin_amdgcn_cvt_pk_f32_fp8((int)q.y, true);
      a[4] += __builtin_amdgcn_cvt_pk_f32_fp8((int)q.z, false);
      a[5] += __builtin_amdgcn_cvt_pk_f32_fp8((int)q.z, true);
      a[6] += __builtin_amdgcn_cvt_pk_f32_fp8((int)q.w, false);
      a[7] += __builtin_amdgcn_cvt_pk_f32_fp8((int)q.w, true);
    };

    int p = base + e;
    int g = 0;
    for (; g + 2 <= ng; g += 2, p += 16) {
      int s0 = csr[p];
      int s1 = csr[p + 8];
      uint4 q0 = xs4[((unsigned int)s0 << 3) | (unsigned int)c];
      uint4 q1 = xs4[((unsigned int)s1 << 3) | (unsigned int)c];
      acc8(q0);
      acc8(q1);
    }
    if (g < ng) {
      int s0 = csr[p];
      uint4 q0 = xs4[((unsigned int)s0 << 3) | (unsigned int)c];
      acc8(q0);
    }

    // butterfly reduce over e (lane bits 3..5)
    #pragma unroll
    for (int m = 8; m <= 32; m <<= 1) {
      #pragma unroll
      for (int j = 0; j < 8; ++j) {
        f32x2 t;
        t[0] = __shfl_xor(a[j][0], m);
        t[1] = __shfl_xor(a[j][1], m);
        a[j] += t;
      }
    }

    if (e == 0) {
      float dn = dinv[n] * FP8_INV;
      float bf[16] = {bb0.x, bb0.y, bb0.z, bb0.w,
                      bb1.x, bb1.y, bb1.z, bb1.w,
                      bb2.x, bb2.y, bb2.z, bb2.w,
                      bb3.x, bb3.y, bb3.z, bb3.w};
      __half2 hh[8];
      #pragma unroll
      for (int j = 0; j < 8; ++j) {
        float rx = fmaf(a[j][0], dn, bf[2 * j]);
        float ry = fmaf(a[j][1], dn, bf[2 * j + 1]);
        hh[j] = __floats2half2_rn(fmaxf(rx, 0.f), fmaxf(ry, 0.f));
      }
      __half* orow = out + (size_t)n * CH + c * 16;
      *(uint4*)orow = *(uint4*)&hh[0];
      *(uint4*)(orow + 8) = *(uint4*)&hh[4];
    }
  }
}

// ---------------------------------------------------------------------------
// Pool + graph boundaries (batch sorted)
// ---------------------------------------------------------------------------
__global__ __launch_bounds__(128) void k_pool(
    const __half* __restrict__ h, const int* __restrict__ batch,
    float* __restrict__ gsum, int* __restrict__ gstart,
    int* __restrict__ gend, int N) {
  int ch = threadIdx.x;
  int n0 = blockIdx.x * 128;
  int n1 = n0 + 128; if (n1 > N) n1 = N;
  if (n0 >= N) return;
  for (int n = n0 + ch; n < n1; n += 128) {
    int g = batch[n];
    if (n == 0 || batch[n - 1] != g) gstart[g] = n;
    if (n == N - 1 || batch[n + 1] != g) gend[g] = n + 1;
  }
  float acc = 0.f;
  int curg = batch[n0];
  for (int n = n0; n < n1; ++n) {
    int g = batch[n];
    if (g != curg) {
      atomicAdd(&gsum[curg * CH + ch], acc);
      acc = 0.f; curg = g;
    }
    acc += __half2float(h[(size_t)n * CH + ch]);
  }
  atomicAdd(&gsum[curg * CH + ch], acc);
}

// ---------------------------------------------------------------------------
// FC
// ---------------------------------------------------------------------------
__global__ __launch_bounds__(64) void k_fc(
    const float* __restrict__ gsum, const int* __restrict__ gstart,
    const int* __restrict__ gend, const float* __restrict__ Wfc,
    const float* __restrict__ bfc, float* __restrict__ outp) {
  int g = blockIdx.x;
  int j = threadIdx.x;
  if (j >= NCLS) return;
  int cnt = gend[g] - gstart[g];
  float invc = 1.0f / fmaxf((float)cnt, 1.0f);
  float acc = 0.0f;
  for (int c = 0; c < CH; ++c)
    acc = fmaf(gsum[g * CH + c], Wfc[c * NCLS + j], acc);
  outp[g * NCLS + j] = fmaf(acc, invc, bfc[j]);
}

// ---------------------------------------------------------------------------
extern "C" void kernel_launch(void* const* d_in, const int* in_sizes, int n_in,
                              void* d_out, int out_size, void* d_ws, size_t ws_size,
                              hipStream_t stream) {
  const float* x    = (const float*)d_in[0];
  const int*   ei   = (const int*)d_in[1];
  const int*   batch= (const int*)d_in[2];
  const float* W1   = (const float*)d_in[3];
  const float* b1   = (const float*)d_in[4];
  const float* W2   = (const float*)d_in[5];
  const float* b2   = (const float*)d_in[6];
  const float* Wfc  = (const float*)d_in[7];
  const float* bfc  = (const float*)d_in[8];
  float* outp = (float*)d_out;

  const int N = in_sizes[0] / CH;       // 100000
  const int E = in_sizes[1] / 2;        // 3200000
  const int* src = ei;
  const int* dst = ei + E;
  const int NBUCK = (N + BW - 1) >> BSHIFT;   // 391
  // Over-allocated bucket capacity: mean + mean/8 (~11 sigma) + worst-case
  // self+pad growth (8 per node * 256 nodes = 2048) + slack; 8-aligned.
  int CAP = (E / NBUCK) + (E / NBUCK) / 8 + 2048 + 256;
  CAP = (CAP + 7) & ~7;

  // Workspace carve (256B aligned). First three buffers zeroed by ONE memset.
  char* w = (char*)d_ws;
  size_t o = 0;
  auto carve = [&](size_t bytes) -> void* {
    o = (o + 255) & ~(size_t)255;
    void* p = w + o;
    o += bytes;
    return p;
  };
  float*    gsum   = (float*)   carve((size_t)NGRAPH * CH * 4);  // zeroed
  int*      gstart = (int*)     carve((size_t)NGRAPH * 4);       // zeroed
  int*      gend   = (int*)     carve((size_t)NGRAPH * 4);       // zeroed
  size_t zbytes = o;
  int*      offs   = (int*)     carve((size_t)N * 4);
  int*      oendb  = (int*)     carve((size_t)N * 4);
  int*      gcur   = (int*)     carve(MAXB * 4);
  int*      csr    = (int*)     carve((size_t)NBUCK * CAP * 4);
  float*    dinv   = (float*)   carve((size_t)N * 4);
  _Float16* WhT1   = (_Float16*)carve((size_t)CH * CH * 2);
  _Float16* WhT2   = (_Float16*)carve((size_t)CH * CH * 2);
  unsigned char* xsbuf = (unsigned char*)carve((size_t)(N + 1) * CH); // fp8 + zero row
  __half*   hbuf   = (__half*)  carve((size_t)N * CH * 2);            // fp16 h
  (void)ws_size;

  // ebuf (packed edges, gapped) aliases hbuf: NBUCK*CAP*4 ~ 18MB <= 25.6MB
  int* ebuf = (int*)hbuf;

  (void)hipMemsetAsync(gsum, 0, zbytes, stream);

  const int GB64 = (N + 63) / 64;       // 1563
  const int GB   = (N + 127) / 128;
  // k_agg: grid-stride, 1 node/wave, 4 waves/block, 2048 blocks (8192 waves)
  int AB = (N + 3) / 4;
  if (AB > 2048) AB = 2048;

  k_init_wt<<<129, 256, 0, stream>>>(gcur, CAP, NBUCK,
                                     (int*)(xsbuf + (size_t)N * CH),
                                     W1, W2, WhT1, WhT2);
  k_scatter<<<(E + 8191) / 8192, 1024, 0, stream>>>(src, dst, gcur, ebuf, E);
  k_build  <<<NBUCK, 1024, 0, stream>>>(ebuf, gcur, offs, oendb, dinv, csr, N, CAP);

  // Layer 1: xs = fp8((x@W1)*dinv*64) ; h = fp16(relu(agg(xs)*dinv/64 + b1))
  k_gemm_f32<<<GB64, 256, 0, stream>>>(x, WhT1, dinv, xsbuf, N);
  k_agg<<<AB, 256, 0, stream>>>((const uint4*)xsbuf, csr, offs, oendb, dinv, b1, hbuf, N);
  // Layer 2
  k_gemm_f16<<<GB64, 256, 0, stream>>>((const _Float16*)hbuf, WhT2, dinv, xsbuf, N);
  k_agg<<<AB, 256, 0, stream>>>((const uint4*)xsbuf, csr, offs, oendb, dinv, b2, hbuf, N);

  // Pool (+ boundaries) + FC
  k_pool<<<GB, 128, 0, stream>>>(hbuf, batch, gsum, gstart, gend, N);
  k_fc<<<NGRAPH, 64, 0, stream>>>(gsum, gstart, gend, Wfc, bfc, outp);
  (void)out_size; (void)n_in;
}

// Round 6
// 333.403 us; speedup vs baseline: 1.4269x; 1.1846x over previous
//
#include <hip/hip_runtime.h>
#include <hip/hip_bf16.h>
#include <hip/hip_fp16.h>

// Problem constants (match reference)
static constexpr int CH     = 128;   // IN_CH == HID
static constexpr int NCLS   = 32;
static constexpr int NGRAPH = 256;

// Bucketed CSR build: buckets are 256-node ranges (bucket = dst >> 8).
static constexpr int BSHIFT = 8;
static constexpr int BW     = 1 << BSHIFT;   // 256 nodes per bucket
static constexpr int MAXB   = 512;

typedef _Float16 half8 __attribute__((ext_vector_type(8)));
typedef _Float16 half4 __attribute__((ext_vector_type(4)));
typedef float    f32x4 __attribute__((ext_vector_type(4)));
typedef float    f32x2 __attribute__((ext_vector_type(2)));

// fp8 (OCP e4m3) gather buffer, row-major [N+1][128] (row N = zero pad row).
// Empirics R0-R5: agg is bound by random 128B-granule request rate
// (~52-58k/us) and/or wave-VMEM instr rate (~60k/us). R6 keeps R3's proven
// loop structure but packs 2 edge-rows per dword instruction (e=lane>>5,
// c=lane&31): instructions halve, requests unchanged -> model discriminator.
static constexpr float FP8_SCALE = 64.0f;
static constexpr float FP8_INV   = 1.0f / 64.0f;

__device__ __forceinline__ unsigned char enc8(float v) {
  return (unsigned char)(__builtin_amdgcn_cvt_pk_fp8_f32(v, v, 0, false) & 0xFF);
}

// ---------------------------------------------------------------------------
// 1) scatter packed edges into over-allocated bucket regions.
//    pack = (dstlo << 17) | src   (dstlo < 256 -> 8 bits; src < 2^17)
//    gcur is pre-zeroed (tiny memset); ebuf index = b*CAP + local offset.
//    Block 0 also zeroes the fp8 pad row (row N of xs).
// ---------------------------------------------------------------------------
__global__ __launch_bounds__(1024) void k_scatter(
    const int* __restrict__ src, const int* __restrict__ dst,
    int* __restrict__ gcur, int* __restrict__ ebuf, int E, int CAP,
    int* __restrict__ xzero) {
  __shared__ int bcnt[MAXB];
  __shared__ int bbase[MAXB];
  int t = threadIdx.x;
  if (blockIdx.x == 0 && t < 32) xzero[t] = 0;   // 128B zero row
  if (t < MAXB) bcnt[t] = 0;
  __syncthreads();
  int base = blockIdx.x * 8192;
  int s_[8], d_[8], r_[8];
  #pragma unroll
  for (int j = 0; j < 8; ++j) {
    int i = base + j * 1024 + t;
    if (i < E) {
      s_[j] = src[i];
      d_[j] = dst[i];
      r_[j] = atomicAdd(&bcnt[d_[j] >> BSHIFT], 1);
    }
  }
  __syncthreads();
  if (t < MAXB && bcnt[t]) bbase[t] = atomicAdd(&gcur[t], bcnt[t]);
  __syncthreads();
  #pragma unroll
  for (int j = 0; j < 8; ++j) {
    int i = base + j * 1024 + t;
    if (i < E) {
      int b = d_[j] >> BSHIFT;
      int p = ((d_[j] & (BW - 1)) << 17) | s_[j];
      ebuf[b * CAP + bbase[b] + r_[j]] = p;
    }
  }
}

// ---------------------------------------------------------------------------
// 2) per-bucket CSR build (packed edges, gapped CAP regions), R3-proven
//    4-aligned layout (pads -> zero row N; self handled in agg init).
//    Blocks 0..31 additionally do the W1/W2 -> fp16 transpose (was its own
//    kernel; folds into otherwise-idle capacity, saves a launch).
// ---------------------------------------------------------------------------
__global__ __launch_bounds__(1024) void k_build(
    const int* __restrict__ ebuf, const int* __restrict__ gcur,
    int* __restrict__ offs, int* __restrict__ oend,
    float* __restrict__ dinv, int* __restrict__ csr, int N, int CAP,
    const float* __restrict__ W1, const float* __restrict__ W2,
    _Float16* __restrict__ WhT1, _Float16* __restrict__ WhT2) {
  __shared__ int sdeg[BW];
  __shared__ int sscan[BW];
  int b = blockIdx.x;
  int t = threadIdx.x;

  // folded weight transpose (2*128*128 elements over blocks 0..31)
  int gi = b * 1024 + t;
  if (gi < 2 * CH * CH) {
    const float* W = (gi < CH * CH) ? W1 : W2;
    _Float16* T   = (gi < CH * CH) ? WhT1 : WhT2;
    int j = gi & (CH * CH - 1);
    int k = j >> 7, n = j & 127;
    T[n * CH + k] = (_Float16)W[j];
  }

  int lo = b << BSHIFT;
  int e0 = b * CAP;
  int e1 = e0 + gcur[b];             // gcur[b] = bucket count after scatter

  if (t < BW) sdeg[t] = 0;
  __syncthreads();
  for (int e = e0 + t; e < e1; e += 1024)
    atomicAdd(&sdeg[ebuf[e] >> 17], 1);
  __syncthreads();
  if (t < BW) sscan[t] = (sdeg[t] + 3) & ~3;     // padded degree
  __syncthreads();
  for (int st = 1; st < BW; st <<= 1) {
    int v = (t < BW && t >= st) ? sscan[t - st] : 0;
    __syncthreads();
    if (t < BW) sscan[t] += v;
    __syncthreads();
  }
  if (t < BW) {
    int deg  = sdeg[t];
    int pdeg = (deg + 3) & ~3;
    int ex = b * CAP + sscan[t] - pdeg;          // 4-aligned (CAP%4==0)
    int n = lo + t;
    if (n < N) {
      offs[n] = ex;
      oend[n] = ex + deg;
      dinv[n] = 1.0f / sqrtf((float)(deg + 1));
      for (int q = deg; q < pdeg; ++q) csr[ex + q] = N;   // zero-row pad
    }
    sscan[t] = ex;                                // fill cursor
  }
  __syncthreads();
  for (int e = e0 + t; e < e1; e += 1024) {
    int p = ebuf[e];
    int pos = atomicAdd(&sscan[p >> 17], 1);
    csr[pos] = p & 0x1FFFF;
  }
}

// ---------------------------------------------------------------------------
// MFMA GEMM: 64-row tiles, 4 waves x 16 rows, K=128 single shot, epilogue
// scales by dinv*64 -> fp8 e4m3 row-major [row][ch].
// ---------------------------------------------------------------------------
__device__ __forceinline__ void stage_w(const _Float16* __restrict__ WhT,
                                        _Float16 (*Ws)[136], int tid) {
  #pragma unroll
  for (int l = 0; l < 8; ++l) {
    int idx = tid + l * 256;            // 0..2047 half8 chunks
    int n = idx >> 4, k8 = (idx & 15) << 3;
    *(half8*)&Ws[n][k8] = *(const half8*)(WhT + n * CH + k8);
  }
}

__device__ __forceinline__ void gemm_core64(
    const _Float16 (*As)[136], const _Float16 (*Ws)[136],
    const float* __restrict__ dinv, unsigned char* __restrict__ C,
    int row0, int M, int tid) {
  int lane = tid & 63, wave = tid >> 6;
  int quad = lane >> 4, sub = lane & 15;
  int m0 = wave * 16;

  f32x4 acc[8];
  #pragma unroll
  for (int j = 0; j < 8; ++j) acc[j] = (f32x4){0.f, 0.f, 0.f, 0.f};

  #pragma unroll
  for (int kc = 0; kc < 4; ++kc) {
    int ko = kc * 32 + quad * 8;
    half8 a = *(const half8*)&As[m0 + sub][ko];
    #pragma unroll
    for (int nt = 0; nt < 8; ++nt) {
      half8 b = *(const half8*)&Ws[nt * 16 + sub][ko];
      acc[nt] = __builtin_amdgcn_mfma_f32_16x16x32_f16(a, b, acc[nt], 0, 0, 0);
    }
  }
  #pragma unroll
  for (int r = 0; r < 4; ++r) {
    int row = row0 + m0 + quad * 4 + r;
    if (row < M) {
      float d = dinv[row] * FP8_SCALE;
      #pragma unroll
      for (int nt = 0; nt < 8; ++nt)
        C[(size_t)row * CH + nt * 16 + sub] = enc8(acc[nt][r] * d);
    }
  }
}

// A input fp32 (layer 1: x), packed half4 LDS stores
__global__ __launch_bounds__(256) void k_gemm_f32(
    const float* __restrict__ A, const _Float16* __restrict__ WhT,
    const float* __restrict__ dinv, unsigned char* __restrict__ C, int M) {
  __shared__ _Float16 As[64][136];
  __shared__ _Float16 Ws[128][136];
  int tid = threadIdx.x;
  int row0 = blockIdx.x * 64;
  #pragma unroll
  for (int l = 0; l < 8; ++l) {
    int idx = tid + l * 256;
    int r = idx >> 5, c4 = (idx & 31) << 2;
    int rr = row0 + r; if (rr >= M) rr = M - 1;
    float4 v = *(const float4*)(A + (size_t)rr * CH + c4);
    half4 hv = { (_Float16)v.x, (_Float16)v.y, (_Float16)v.z, (_Float16)v.w };
    *(half4*)&As[r][c4] = hv;
  }
  stage_w(WhT, Ws, tid);
  __syncthreads();
  gemm_core64(As, Ws, dinv, C, row0, M, tid);
}

// A input fp16 (layer 2: h)
__global__ __launch_bounds__(256) void k_gemm_f16(
    const _Float16* __restrict__ A, const _Float16* __restrict__ WhT,
    const float* __restrict__ dinv, unsigned char* __restrict__ C, int M) {
  __shared__ _Float16 As[64][136];
  __shared__ _Float16 Ws[128][136];
  int tid = threadIdx.x;
  int row0 = blockIdx.x * 64;
  #pragma unroll
  for (int l = 0; l < 4; ++l) {
    int idx = tid + l * 256;
    int r = idx >> 4, c8 = (idx & 15) << 3;
    int rr = row0 + r; if (rr >= M) rr = M - 1;
    *(half8*)&As[r][c8] = *(const half8*)(A + (size_t)rr * CH + c8);
  }
  stage_w(WhT, Ws, tid);
  __syncthreads();
  gemm_core64(As, Ws, dinv, C, row0, M, tid);
}

// ---------------------------------------------------------------------------
// Aggregation (pull, CSR): R3's proven 2-node lockstep + prefetch structure,
// but 2 EDGE-ROWS PER DWORD INSTRUCTION: e = lane>>5 selects which edge of a
// pair, c = lane&31 is the dword (4 fp8 channels) within the 128B row. One
// gather instruction covers 2 edges (same request count as R3, half the
// instructions). Self row initialized on e==0 lanes only; final shfl_xor(32)
// folds the two edge slots; lanes e==0 write the output row.
// ---------------------------------------------------------------------------
__global__ __launch_bounds__(256) void k_agg(
    const unsigned int* __restrict__ xs32, const int* __restrict__ csr,
    const int* __restrict__ offs, const int* __restrict__ oend,
    const float* __restrict__ dinv, const float* __restrict__ bias,
    __half* __restrict__ out, int N) {
  int lane  = threadIdx.x & 63;
  int wid0  = blockIdx.x * 4 + (threadIdx.x >> 6);
  int wstep = gridDim.x * 4;
  int e = lane >> 5;                    // edge slot within pair
  unsigned int c = lane & 31;           // dword index within row
  float4 bb = *(const float4*)(bias + c * 4);

  auto G = [&](int s) -> unsigned int {
    return xs32[((unsigned int)s << 5) | c];
  };

  for (int wid = wid0; wid * 2 < N; wid += wstep) {
    int nA = wid * 2, nB = nA + 1;
    bool hasB = (nB < N);

    int eA = offs[nA];
    int cA = (oend[nA] - eA + 3) >> 2;                 // int4 chunk count
    int eB = hasB ? offs[nB] : eA;
    int cB = hasB ? ((oend[nB] - eB + 3) >> 2) : 0;

    f32x2 a0 = {0.f, 0.f}, a1 = {0.f, 0.f};
    f32x2 b0 = {0.f, 0.f}, b1 = {0.f, 0.f};
    if (e == 0) {                        // self row, counted once
      unsigned int ow = G(nA);
      a0 = __builtin_amdgcn_cvt_pk_f32_fp8((int)ow, false);
      a1 = __builtin_amdgcn_cvt_pk_f32_fp8((int)ow, true);
      if (hasB) {
        unsigned int ob = G(nB);
        b0 = __builtin_amdgcn_cvt_pk_f32_fp8((int)ob, false);
        b1 = __builtin_amdgcn_cvt_pk_f32_fp8((int)ob, true);
      }
    }

    #define ACC(d, x0, x1) \
      x0 += __builtin_amdgcn_cvt_pk_f32_fp8((int)(d), false); \
      x1 += __builtin_amdgcn_cvt_pk_f32_fp8((int)(d), true);

    // lockstep main: 8 dword gathers (16 edges) in flight, csr prefetched
    if (cA >= 2 && cB >= 2) {
      int4 ca0 = *(const int4*)(csr + eA);
      int4 ca1 = *(const int4*)(csr + eA + 4);
      int4 cb0 = *(const int4*)(csr + eB);
      int4 cb1 = *(const int4*)(csr + eB + 4);
      do {
        int sA0 = e ? ca0.y : ca0.x, sA1 = e ? ca0.w : ca0.z;
        int sA2 = e ? ca1.y : ca1.x, sA3 = e ? ca1.w : ca1.z;
        int sB0 = e ? cb0.y : cb0.x, sB1 = e ? cb0.w : cb0.z;
        int sB2 = e ? cb1.y : cb1.x, sB3 = e ? cb1.w : cb1.z;
        unsigned int dA0 = G(sA0), dA1 = G(sA1), dA2 = G(sA2), dA3 = G(sA3);
        unsigned int dB0 = G(sB0), dB1 = G(sB1), dB2 = G(sB2), dB3 = G(sB3);
        eA += 8; eB += 8; cA -= 2; cB -= 2;
        int4 na0 = *(const int4*)(csr + eA);
        int4 na1 = *(const int4*)(csr + eA + 4);
        int4 nb0 = *(const int4*)(csr + eB);
        int4 nb1 = *(const int4*)(csr + eB + 4);
        ACC(dA0, a0, a1); ACC(dA1, a0, a1); ACC(dA2, a0, a1); ACC(dA3, a0, a1);
        ACC(dB0, b0, b1); ACC(dB1, b0, b1); ACC(dB2, b0, b1); ACC(dB3, b0, b1);
        ca0 = na0; ca1 = na1; cb0 = nb0; cb1 = nb1;
      } while (cA >= 2 && cB >= 2);
    }

    // per-node drain: 2-chunk (4 gathers = 8 edges) then 1-chunk
    auto drain = [&](int ee, int cc, f32x2& x0, f32x2& x1) {
      while (cc >= 2) {
        int4 q0 = *(const int4*)(csr + ee);
        int4 q1 = *(const int4*)(csr + ee + 4);
        int s0 = e ? q0.y : q0.x, s1 = e ? q0.w : q0.z;
        int s2 = e ? q1.y : q1.x, s3 = e ? q1.w : q1.z;
        unsigned int d0 = G(s0), d1 = G(s1), d2 = G(s2), d3 = G(s3);
        ACC(d0, x0, x1); ACC(d1, x0, x1); ACC(d2, x0, x1); ACC(d3, x0, x1);
        ee += 8; cc -= 2;
      }
      if (cc > 0) {
        int4 q0 = *(const int4*)(csr + ee);
        int s0 = e ? q0.y : q0.x, s1 = e ? q0.w : q0.z;
        unsigned int d0 = G(s0), d1 = G(s1);
        ACC(d0, x0, x1); ACC(d1, x0, x1);
      }
    };
    drain(eA, cA, a0, a1);
    if (hasB) drain(eB, cB, b0, b1);
    #undef ACC

    // fold the two edge slots (lane ^ 32)
    a0[0] += __shfl_xor(a0[0], 32); a0[1] += __shfl_xor(a0[1], 32);
    a1[0] += __shfl_xor(a1[0], 32); a1[1] += __shfl_xor(a1[1], 32);
    if (hasB) {
      b0[0] += __shfl_xor(b0[0], 32); b0[1] += __shfl_xor(b0[1], 32);
      b1[0] += __shfl_xor(b1[0], 32); b1[1] += __shfl_xor(b1[1], 32);
    }

    if (e == 0) {
      {
        float dn = dinv[nA] * FP8_INV;
        float r0 = fmaf(a0[0], dn, bb.x), r1 = fmaf(a0[1], dn, bb.y);
        float r2 = fmaf(a1[0], dn, bb.z), r3 = fmaf(a1[1], dn, bb.w);
        __half2 h0 = __floats2half2_rn(fmaxf(r0, 0.f), fmaxf(r1, 0.f));
        __half2 h1 = __floats2half2_rn(fmaxf(r2, 0.f), fmaxf(r3, 0.f));
        __half2* op = (__half2*)(out + (size_t)nA * CH + c * 4);
        op[0] = h0; op[1] = h1;
      }
      if (hasB) {
        float dn = dinv[nB] * FP8_INV;
        float r0 = fmaf(b0[0], dn, bb.x), r1 = fmaf(b0[1], dn, bb.y);
        float r2 = fmaf(b1[0], dn, bb.z), r3 = fmaf(b1[1], dn, bb.w);
        __half2 h0 = __floats2half2_rn(fmaxf(r0, 0.f), fmaxf(r1, 0.f));
        __half2 h1 = __floats2half2_rn(fmaxf(r2, 0.f), fmaxf(r3, 0.f));
        __half2* op = (__half2*)(out + (size_t)nB * CH + c * 4);
        op[0] = h0; op[1] = h1;
      }
    }
  }
}

// ---------------------------------------------------------------------------
// Fused pool + FC: one block per graph. Boundaries found by binary search on
// the sorted batch array (no gstart/gend buffers, no gsum atomics, no memset).
// ---------------------------------------------------------------------------
__global__ __launch_bounds__(256) void k_poolfc(
    const __half* __restrict__ h, const int* __restrict__ batch,
    const float* __restrict__ Wfc, const float* __restrict__ bfc,
    float* __restrict__ outp, int N) {
  __shared__ float sred[256][2];
  __shared__ float gs[CH];
  int g = blockIdx.x;
  int t = threadIdx.x;

  // lower_bound(batch, g) / lower_bound(batch, g+1)
  int lo = 0, hi = N;
  while (lo < hi) { int m = (lo + hi) >> 1; if (batch[m] < g) lo = m + 1; else hi = m; }
  int s0 = lo;
  hi = N;
  while (lo < hi) { int m = (lo + hi) >> 1; if (batch[m] < g + 1) lo = m + 1; else hi = m; }
  int s1 = lo;

  int ch2 = t & 63;         // half2 (2 channels)
  int rh  = t >> 6;         // 4-way row split
  const __half2* h2 = (const __half2*)h;
  float ax = 0.f, ay = 0.f;
  for (int n = s0 + rh; n < s1; n += 4) {
    float2 v = __half22float2(h2[(size_t)n * 64 + ch2]);
    ax += v.x; ay += v.y;
  }
  sred[t][0] = ax; sred[t][1] = ay;
  __syncthreads();
  if (t < 64) {
    float invc = 1.0f / fmaxf((float)(s1 - s0), 1.0f);
    float sx = sred[t][0] + sred[t + 64][0] + sred[t + 128][0] + sred[t + 192][0];
    float sy = sred[t][1] + sred[t + 64][1] + sred[t + 128][1] + sred[t + 192][1];
    gs[2 * t]     = sx * invc;
    gs[2 * t + 1] = sy * invc;
  }
  __syncthreads();
  if (t < NCLS) {
    float acc = bfc[t];
    #pragma unroll 8
    for (int cc = 0; cc < CH; ++cc)
      acc = fmaf(gs[cc], Wfc[cc * NCLS + t], acc);
    outp[g * NCLS + t] = acc;
  }
}

// ---------------------------------------------------------------------------
extern "C" void kernel_launch(void* const* d_in, const int* in_sizes, int n_in,
                              void* d_out, int out_size, void* d_ws, size_t ws_size,
                              hipStream_t stream) {
  const float* x    = (const float*)d_in[0];
  const int*   ei   = (const int*)d_in[1];
  const int*   batch= (const int*)d_in[2];
  const float* W1   = (const float*)d_in[3];
  const float* b1   = (const float*)d_in[4];
  const float* W2   = (const float*)d_in[5];
  const float* b2   = (const float*)d_in[6];
  const float* Wfc  = (const float*)d_in[7];
  const float* bfc  = (const float*)d_in[8];
  float* outp = (float*)d_out;

  const int N = in_sizes[0] / CH;       // 100000
  const int E = in_sizes[1] / 2;        // 3200000
  const int* src = ei;
  const int* dst = ei + E;
  const int NBUCK = (N + BW - 1) >> BSHIFT;   // 391
  // Over-allocated bucket capacity: mean + ~11 sigma + 4-align padding room.
  int CAP = (E / NBUCK) + (E / NBUCK) / 8 + 1280;
  CAP = (CAP + 3) & ~3;                       // keep per-bucket base 4-aligned

  // Workspace carve (256B aligned).
  char* w = (char*)d_ws;
  size_t o = 0;
  auto carve = [&](size_t bytes) -> void* {
    o = (o + 255) & ~(size_t)255;
    void* p = w + o;
    o += bytes;
    return p;
  };
  int*      offs   = (int*)     carve((size_t)N * 4);
  int*      oendb  = (int*)     carve((size_t)N * 4);
  int*      gcur   = (int*)     carve(MAXB * 4);                 // zeroed
  int*      csr    = (int*)     carve((size_t)NBUCK * CAP * 4);
  float*    dinv   = (float*)   carve((size_t)N * 4);
  _Float16* WhT1   = (_Float16*)carve((size_t)CH * CH * 2);
  _Float16* WhT2   = (_Float16*)carve((size_t)CH * CH * 2);
  unsigned char* xsbuf = (unsigned char*)carve((size_t)(N + 1) * CH); // fp8 + zero row
  __half*   hbuf   = (__half*)  carve((size_t)N * CH * 2);            // fp16 h
  (void)ws_size;

  // ebuf (packed edges, gapped) aliases hbuf: NBUCK*CAP*4 ~ 16.4MB <= 25.6MB
  int* ebuf = (int*)hbuf;

  (void)hipMemsetAsync(gcur, 0, MAXB * 4, stream);

  const int GB64 = (N + 63) / 64;       // 1563
  // k_agg: grid-stride, 2 nodes/wave, 4 waves/block, 2048 blocks (8192 waves)
  int AB = (N + 7) / 8;
  if (AB > 2048) AB = 2048;

  k_scatter<<<(E + 8191) / 8192, 1024, 0, stream>>>(
      src, dst, gcur, ebuf, E, CAP, (int*)(xsbuf + (size_t)N * CH));
  k_build<<<NBUCK, 1024, 0, stream>>>(ebuf, gcur, offs, oendb, dinv, csr,
                                      N, CAP, W1, W2, WhT1, WhT2);

  // Layer 1: xs = fp8((x@W1)*dinv*64) ; h = fp16(relu(agg(xs)*dinv/64 + b1))
  k_gemm_f32<<<GB64, 256, 0, stream>>>(x, WhT1, dinv, xsbuf, N);
  k_agg<<<AB, 256, 0, stream>>>((const unsigned int*)xsbuf, csr, offs, oendb,
                                dinv, b1, hbuf, N);
  // Layer 2
  k_gemm_f16<<<GB64, 256, 0, stream>>>((const _Float16*)hbuf, WhT2, dinv, xsbuf, N);
  k_agg<<<AB, 256, 0, stream>>>((const unsigned int*)xsbuf, csr, offs, oendb,
                                dinv, b2, hbuf, N);

  // Fused pool + FC (one block per graph, binary-search boundaries)
  k_poolfc<<<NGRAPH, 256, 0, stream>>>(hbuf, batch, Wfc, bfc, outp, N);
  (void)out_size; (void)n_in;
}

// Round 7
// 326.868 us; speedup vs baseline: 1.4555x; 1.0200x over previous
//
#include <hip/hip_runtime.h>
#include <hip/hip_bf16.h>
#include <hip/hip_fp16.h>

// Problem constants (match reference)
static constexpr int CH     = 128;   // IN_CH == HID
static constexpr int NCLS   = 32;
static constexpr int NGRAPH = 256;

// Bucketed CSR build: buckets are 256-node ranges (bucket = dst >> 8).
static constexpr int BSHIFT = 8;
static constexpr int BW     = 1 << BSHIFT;   // 256 nodes per bucket
static constexpr int MAXB   = 512;

typedef _Float16 half8 __attribute__((ext_vector_type(8)));
typedef _Float16 half4 __attribute__((ext_vector_type(4)));
typedef float    f32x4 __attribute__((ext_vector_type(4)));
typedef float    f32x2 __attribute__((ext_vector_type(2)));

// fp8 (OCP e4m3) gather buffer, row-major [N+1][128] (row N = zero pad row).
static constexpr float FP8_SCALE = 64.0f;
static constexpr float FP8_INV   = 1.0f / 64.0f;

__device__ __forceinline__ unsigned char enc8(float v) {
  return (unsigned char)(__builtin_amdgcn_cvt_pk_fp8_f32(v, v, 0, false) & 0xFF);
}

// ---------------------------------------------------------------------------
// 1) scatter packed edges into over-allocated bucket regions.
//    pack = (dstlo << 17) | src. NEW: block-local LDS bucket sort, then
//    coalesced copy-out (runs of ~21 consecutive addresses) -- kills the
//    3.2M scattered-4B-store request flood.
// ---------------------------------------------------------------------------
__global__ __launch_bounds__(1024) void k_scatter(
    const int* __restrict__ src, const int* __restrict__ dst,
    int* __restrict__ gcur, int* __restrict__ ebuf, int E, int CAP,
    int* __restrict__ xzero) {
  __shared__ int bcnt[MAXB];               // 2KB
  __shared__ int lofs[MAXB];               // 2KB (inclusive scan)
  __shared__ int bbase[MAXB];              // 2KB
  __shared__ int sorted[8192];             // 32KB
  __shared__ unsigned short sbkt[8192];    // 16KB
  int t = threadIdx.x;
  if (blockIdx.x == 0 && t < 32) xzero[t] = 0;   // 128B fp8 zero row
  if (t < MAXB) bcnt[t] = 0;
  __syncthreads();
  int base = blockIdx.x * 8192;
  int cnt = E - base; if (cnt > 8192) cnt = 8192;
  int p_[8], b_[8], r_[8];
  #pragma unroll
  for (int j = 0; j < 8; ++j) {
    int i = j * 1024 + t;
    if (i < cnt) {
      int s = src[base + i], d = dst[base + i];
      b_[j] = d >> BSHIFT;
      p_[j] = ((d & (BW - 1)) << 17) | s;
      r_[j] = atomicAdd(&bcnt[b_[j]], 1);
    }
  }
  __syncthreads();
  if (t < MAXB) lofs[t] = bcnt[t];
  __syncthreads();
  for (int st = 1; st < MAXB; st <<= 1) {
    int v = (t < MAXB && t >= st) ? lofs[t - st] : 0;
    __syncthreads();
    if (t < MAXB) lofs[t] += v;
    __syncthreads();
  }
  if (t < MAXB && bcnt[t]) bbase[t] = atomicAdd(&gcur[t], bcnt[t]);
  __syncthreads();
  #pragma unroll
  for (int j = 0; j < 8; ++j) {
    int i = j * 1024 + t;
    if (i < cnt) {
      int pos = lofs[b_[j]] - bcnt[b_[j]] + r_[j];   // exclusive start + rank
      sorted[pos] = p_[j];
      sbkt[pos] = (unsigned short)b_[j];
    }
  }
  __syncthreads();
  for (int i = t; i < cnt; i += 1024) {
    int bk = sbkt[i];
    ebuf[bk * CAP + bbase[bk] + (i - (lofs[bk] - bcnt[bk]))] = sorted[i];
  }
}

// ---------------------------------------------------------------------------
// 2) per-bucket CSR build. Histogram + scan as before (4-aligned regions,
//    zero-row pads). NEW fill: chunked LDS node-sort then coalesced copy-out
//    at per-node cursors (runs of ~32) -- kills the 3.3M scattered-store
//    flood. Blocks 0..31 also fold in the W1/W2 fp16 transpose.
// ---------------------------------------------------------------------------
__global__ __launch_bounds__(1024) void k_build(
    const int* __restrict__ ebuf, const int* __restrict__ gcur,
    int* __restrict__ offs, int* __restrict__ oend,
    float* __restrict__ dinv, int* __restrict__ csr, int N, int CAP,
    const float* __restrict__ W1, const float* __restrict__ W2,
    _Float16* __restrict__ WhT1, _Float16* __restrict__ WhT2) {
  __shared__ int sdeg[BW];                 // 1KB
  __shared__ int sscan[BW];                // 1KB
  __shared__ int cur[BW];                  // 1KB
  __shared__ int chist[BW];                // 1KB
  __shared__ int clofs[BW];                // 1KB
  __shared__ int lsorted[8192];            // 32KB
  __shared__ unsigned char lnode[8192];    // 8KB
  int b = blockIdx.x;
  int t = threadIdx.x;

  // folded weight transpose (2*128*128 elements over blocks 0..31)
  int gi = b * 1024 + t;
  if (gi < 2 * CH * CH) {
    const float* W = (gi < CH * CH) ? W1 : W2;
    _Float16* T   = (gi < CH * CH) ? WhT1 : WhT2;
    int j = gi & (CH * CH - 1);
    int k = j >> 7, n = j & 127;
    T[n * CH + k] = (_Float16)W[j];
  }

  int lo = b << BSHIFT;
  int e0 = b * CAP;
  int CNT = gcur[b];

  if (t < BW) sdeg[t] = 0;
  __syncthreads();
  for (int i = t; i < CNT; i += 1024)
    atomicAdd(&sdeg[ebuf[e0 + i] >> 17], 1);
  __syncthreads();
  if (t < BW) sscan[t] = (sdeg[t] + 3) & ~3;     // padded degree
  __syncthreads();
  for (int st = 1; st < BW; st <<= 1) {
    int v = (t < BW && t >= st) ? sscan[t - st] : 0;
    __syncthreads();
    if (t < BW) sscan[t] += v;
    __syncthreads();
  }
  if (t < BW) {
    int deg  = sdeg[t];
    int pdeg = (deg + 3) & ~3;
    int ex = b * CAP + sscan[t] - pdeg;          // 4-aligned (CAP%4==0)
    int n = lo + t;
    if (n < N) {
      offs[n] = ex;
      oend[n] = ex + deg;
      dinv[n] = 1.0f / sqrtf((float)(deg + 1));
      for (int q = deg; q < pdeg; ++q) csr[ex + q] = N;   // zero-row pad
      cur[t] = ex;
    }
  }
  __syncthreads();

  // chunked sorted fill
  for (int c0 = 0; c0 < CNT; c0 += 8192) {
    int ccnt = CNT - c0; if (ccnt > 8192) ccnt = 8192;
    if (t < BW) chist[t] = 0;
    __syncthreads();
    int p_[8], nd_[8], r_[8];
    #pragma unroll
    for (int j = 0; j < 8; ++j) {
      int i = j * 1024 + t;
      if (i < ccnt) {
        p_[j] = ebuf[e0 + c0 + i];
        nd_[j] = p_[j] >> 17;
        r_[j] = atomicAdd(&chist[nd_[j]], 1);
      }
    }
    __syncthreads();
    if (t < BW) clofs[t] = chist[t];
    __syncthreads();
    for (int st = 1; st < BW; st <<= 1) {
      int v = (t < BW && t >= st) ? clofs[t - st] : 0;
      __syncthreads();
      if (t < BW) clofs[t] += v;
      __syncthreads();
    }
    #pragma unroll
    for (int j = 0; j < 8; ++j) {
      int i = j * 1024 + t;
      if (i < ccnt) {
        int pos = clofs[nd_[j]] - chist[nd_[j]] + r_[j];
        lsorted[pos] = p_[j];
        lnode[pos] = (unsigned char)nd_[j];
      }
    }
    __syncthreads();
    for (int i = t; i < ccnt; i += 1024) {
      int nd = lnode[i];
      int gpos = cur[nd] + (i - (clofs[nd] - chist[nd]));
      csr[gpos] = lsorted[i] & 0x1FFFF;
    }
    __syncthreads();
    if (t < BW) cur[t] += chist[t];
    __syncthreads();
  }
}

// ---------------------------------------------------------------------------
// waveGemm: Ws staged ONCE per block, then each WAVE independently
// grid-strides over 16-row tiles; A-fragments loaded global->register
// (identical bytes the old LDS path delivered), no per-tile barriers.
// Epilogue scales by dinv*64 -> fp8 e4m3 row-major [row][ch].
// ---------------------------------------------------------------------------
__device__ __forceinline__ void stage_w(const _Float16* __restrict__ WhT,
                                        _Float16 (*Ws)[136], int tid) {
  #pragma unroll
  for (int l = 0; l < 8; ++l) {
    int idx = tid + l * 256;            // 0..2047 half8 chunks
    int n = idx >> 4, k8 = (idx & 15) << 3;
    *(half8*)&Ws[n][k8] = *(const half8*)(WhT + n * CH + k8);
  }
}

__device__ __forceinline__ void gemm_tile(
    const _Float16 (*Ws)[136], const half8* af,
    const float* __restrict__ dinv, unsigned char* __restrict__ C,
    int tile, int M, int quad, int sub) {
  f32x4 acc[8];
  #pragma unroll
  for (int j = 0; j < 8; ++j) acc[j] = (f32x4){0.f, 0.f, 0.f, 0.f};
  #pragma unroll
  for (int kc = 0; kc < 4; ++kc) {
    #pragma unroll
    for (int nt = 0; nt < 8; ++nt) {
      half8 b = *(const half8*)&Ws[nt * 16 + sub][kc * 32 + quad * 8];
      acc[nt] = __builtin_amdgcn_mfma_f32_16x16x32_f16(af[kc], b, acc[nt], 0, 0, 0);
    }
  }
  #pragma unroll
  for (int r = 0; r < 4; ++r) {
    int orow = tile * 16 + quad * 4 + r;
    if (orow < M) {
      float d = dinv[orow] * FP8_SCALE;
      #pragma unroll
      for (int nt = 0; nt < 8; ++nt)
        C[(size_t)orow * CH + nt * 16 + sub] = enc8(acc[nt][r] * d);
    }
  }
}

// A input fp32 (layer 1: x)
__global__ __launch_bounds__(256) void k_gemm_f32(
    const float* __restrict__ A, const _Float16* __restrict__ WhT,
    const float* __restrict__ dinv, unsigned char* __restrict__ C, int M) {
  __shared__ _Float16 Ws[128][136];
  int tid = threadIdx.x;
  stage_w(WhT, Ws, tid);
  __syncthreads();
  int lane = tid & 63;
  int quad = lane >> 4, sub = lane & 15;
  int ntiles = (M + 15) >> 4;
  int wid0 = blockIdx.x * 4 + (tid >> 6);
  int wstep = gridDim.x * 4;
  for (int tile = wid0; tile < ntiles; tile += wstep) {
    int row = tile * 16 + sub; if (row >= M) row = M - 1;
    const float* arow = A + (size_t)row * CH + quad * 8;
    half8 af[4];
    #pragma unroll
    for (int kc = 0; kc < 4; ++kc) {
      float4 v0 = *(const float4*)(arow + kc * 32);
      float4 v1 = *(const float4*)(arow + kc * 32 + 4);
      af[kc] = (half8){(_Float16)v0.x, (_Float16)v0.y, (_Float16)v0.z, (_Float16)v0.w,
                       (_Float16)v1.x, (_Float16)v1.y, (_Float16)v1.z, (_Float16)v1.w};
    }
    gemm_tile(Ws, af, dinv, C, tile, M, quad, sub);
  }
}

// A input fp16 (layer 2: h)
__global__ __launch_bounds__(256) void k_gemm_f16(
    const _Float16* __restrict__ A, const _Float16* __restrict__ WhT,
    const float* __restrict__ dinv, unsigned char* __restrict__ C, int M) {
  __shared__ _Float16 Ws[128][136];
  int tid = threadIdx.x;
  stage_w(WhT, Ws, tid);
  __syncthreads();
  int lane = tid & 63;
  int quad = lane >> 4, sub = lane & 15;
  int ntiles = (M + 15) >> 4;
  int wid0 = blockIdx.x * 4 + (tid >> 6);
  int wstep = gridDim.x * 4;
  for (int tile = wid0; tile < ntiles; tile += wstep) {
    int row = tile * 16 + sub; if (row >= M) row = M - 1;
    const _Float16* arow = A + (size_t)row * CH + quad * 8;
    half8 af[4];
    #pragma unroll
    for (int kc = 0; kc < 4; ++kc)
      af[kc] = *(const half8*)(arow + kc * 32);
    gemm_tile(Ws, af, dinv, C, tile, M, quad, sub);
  }
}

// ---------------------------------------------------------------------------
// Aggregation (pull, CSR): R6 structure unchanged (at the ~55k req/us wall).
// 2 edge-rows per dword instruction (e=lane>>5, c=lane&31), 2-node lockstep,
// csr prefetch, shfl_xor(32) fold.
// ---------------------------------------------------------------------------
__global__ __launch_bounds__(256) void k_agg(
    const unsigned int* __restrict__ xs32, const int* __restrict__ csr,
    const int* __restrict__ offs, const int* __restrict__ oend,
    const float* __restrict__ dinv, const float* __restrict__ bias,
    __half* __restrict__ out, int N) {
  int lane  = threadIdx.x & 63;
  int wid0  = blockIdx.x * 4 + (threadIdx.x >> 6);
  int wstep = gridDim.x * 4;
  int e = lane >> 5;                    // edge slot within pair
  unsigned int c = lane & 31;           // dword index within row
  float4 bb = *(const float4*)(bias + c * 4);

  auto G = [&](int s) -> unsigned int {
    return xs32[((unsigned int)s << 5) | c];
  };

  for (int wid = wid0; wid * 2 < N; wid += wstep) {
    int nA = wid * 2, nB = nA + 1;
    bool hasB = (nB < N);

    int eA = offs[nA];
    int cA = (oend[nA] - eA + 3) >> 2;                 // int4 chunk count
    int eB = hasB ? offs[nB] : eA;
    int cB = hasB ? ((oend[nB] - eB + 3) >> 2) : 0;

    f32x2 a0 = {0.f, 0.f}, a1 = {0.f, 0.f};
    f32x2 b0 = {0.f, 0.f}, b1 = {0.f, 0.f};
    if (e == 0) {                        // self row, counted once
      unsigned int ow = G(nA);
      a0 = __builtin_amdgcn_cvt_pk_f32_fp8((int)ow, false);
      a1 = __builtin_amdgcn_cvt_pk_f32_fp8((int)ow, true);
      if (hasB) {
        unsigned int ob = G(nB);
        b0 = __builtin_amdgcn_cvt_pk_f32_fp8((int)ob, false);
        b1 = __builtin_amdgcn_cvt_pk_f32_fp8((int)ob, true);
      }
    }

    #define ACC(d, x0, x1) \
      x0 += __builtin_amdgcn_cvt_pk_f32_fp8((int)(d), false); \
      x1 += __builtin_amdgcn_cvt_pk_f32_fp8((int)(d), true);

    if (cA >= 2 && cB >= 2) {
      int4 ca0 = *(const int4*)(csr + eA);
      int4 ca1 = *(const int4*)(csr + eA + 4);
      int4 cb0 = *(const int4*)(csr + eB);
      int4 cb1 = *(const int4*)(csr + eB + 4);
      do {
        int sA0 = e ? ca0.y : ca0.x, sA1 = e ? ca0.w : ca0.z;
        int sA2 = e ? ca1.y : ca1.x, sA3 = e ? ca1.w : ca1.z;
        int sB0 = e ? cb0.y : cb0.x, sB1 = e ? cb0.w : cb0.z;
        int sB2 = e ? cb1.y : cb1.x, sB3 = e ? cb1.w : cb1.z;
        unsigned int dA0 = G(sA0), dA1 = G(sA1), dA2 = G(sA2), dA3 = G(sA3);
        unsigned int dB0 = G(sB0), dB1 = G(sB1), dB2 = G(sB2), dB3 = G(sB3);
        eA += 8; eB += 8; cA -= 2; cB -= 2;
        int4 na0 = *(const int4*)(csr + eA);
        int4 na1 = *(const int4*)(csr + eA + 4);
        int4 nb0 = *(const int4*)(csr + eB);
        int4 nb1 = *(const int4*)(csr + eB + 4);
        ACC(dA0, a0, a1); ACC(dA1, a0, a1); ACC(dA2, a0, a1); ACC(dA3, a0, a1);
        ACC(dB0, b0, b1); ACC(dB1, b0, b1); ACC(dB2, b0, b1); ACC(dB3, b0, b1);
        ca0 = na0; ca1 = na1; cb0 = nb0; cb1 = nb1;
      } while (cA >= 2 && cB >= 2);
    }

    auto drain = [&](int ee, int cc, f32x2& x0, f32x2& x1) {
      while (cc >= 2) {
        int4 q0 = *(const int4*)(csr + ee);
        int4 q1 = *(const int4*)(csr + ee + 4);
        int s0 = e ? q0.y : q0.x, s1 = e ? q0.w : q0.z;
        int s2 = e ? q1.y : q1.x, s3 = e ? q1.w : q1.z;
        unsigned int d0 = G(s0), d1 = G(s1), d2 = G(s2), d3 = G(s3);
        ACC(d0, x0, x1); ACC(d1, x0, x1); ACC(d2, x0, x1); ACC(d3, x0, x1);
        ee += 8; cc -= 2;
      }
      if (cc > 0) {
        int4 q0 = *(const int4*)(csr + ee);
        int s0 = e ? q0.y : q0.x, s1 = e ? q0.w : q0.z;
        unsigned int d0 = G(s0), d1 = G(s1);
        ACC(d0, x0, x1); ACC(d1, x0, x1);
      }
    };
    drain(eA, cA, a0, a1);
    if (hasB) drain(eB, cB, b0, b1);
    #undef ACC

    a0[0] += __shfl_xor(a0[0], 32); a0[1] += __shfl_xor(a0[1], 32);
    a1[0] += __shfl_xor(a1[0], 32); a1[1] += __shfl_xor(a1[1], 32);
    if (hasB) {
      b0[0] += __shfl_xor(b0[0], 32); b0[1] += __shfl_xor(b0[1], 32);
      b1[0] += __shfl_xor(b1[0], 32); b1[1] += __shfl_xor(b1[1], 32);
    }

    if (e == 0) {
      {
        float dn = dinv[nA] * FP8_INV;
        float r0 = fmaf(a0[0], dn, bb.x), r1 = fmaf(a0[1], dn, bb.y);
        float r2 = fmaf(a1[0], dn, bb.z), r3 = fmaf(a1[1], dn, bb.w);
        __half2 h0 = __floats2half2_rn(fmaxf(r0, 0.f), fmaxf(r1, 0.f));
        __half2 h1 = __floats2half2_rn(fmaxf(r2, 0.f), fmaxf(r3, 0.f));
        __half2* op = (__half2*)(out + (size_t)nA * CH + c * 4);
        op[0] = h0; op[1] = h1;
      }
      if (hasB) {
        float dn = dinv[nB] * FP8_INV;
        float r0 = fmaf(b0[0], dn, bb.x), r1 = fmaf(b0[1], dn, bb.y);
        float r2 = fmaf(b1[0], dn, bb.z), r3 = fmaf(b1[1], dn, bb.w);
        __half2 h0 = __floats2half2_rn(fmaxf(r0, 0.f), fmaxf(r1, 0.f));
        __half2 h1 = __floats2half2_rn(fmaxf(r2, 0.f), fmaxf(r3, 0.f));
        __half2* op = (__half2*)(out + (size_t)nB * CH + c * 4);
        op[0] = h0; op[1] = h1;
      }
    }
  }
}

// ---------------------------------------------------------------------------
// Fused pool + FC: one block per graph, binary-search boundaries.
// ---------------------------------------------------------------------------
__global__ __launch_bounds__(256) void k_poolfc(
    const __half* __restrict__ h, const int* __restrict__ batch,
    const float* __restrict__ Wfc, const float* __restrict__ bfc,
    float* __restrict__ outp, int N) {
  __shared__ float sred[256][2];
  __shared__ float gs[CH];
  int g = blockIdx.x;
  int t = threadIdx.x;

  int lo = 0, hi = N;
  while (lo < hi) { int m = (lo + hi) >> 1; if (batch[m] < g) lo = m + 1; else hi = m; }
  int s0 = lo;
  hi = N;
  while (lo < hi) { int m = (lo + hi) >> 1; if (batch[m] < g + 1) lo = m + 1; else hi = m; }
  int s1 = lo;

  int ch2 = t & 63;
  int rh  = t >> 6;
  const __half2* h2 = (const __half2*)h;
  float ax = 0.f, ay = 0.f;
  for (int n = s0 + rh; n < s1; n += 4) {
    float2 v = __half22float2(h2[(size_t)n * 64 + ch2]);
    ax += v.x; ay += v.y;
  }
  sred[t][0] = ax; sred[t][1] = ay;
  __syncthreads();
  if (t < 64) {
    float invc = 1.0f / fmaxf((float)(s1 - s0), 1.0f);
    float sx = sred[t][0] + sred[t + 64][0] + sred[t + 128][0] + sred[t + 192][0];
    float sy = sred[t][1] + sred[t + 64][1] + sred[t + 128][1] + sred[t + 192][1];
    gs[2 * t]     = sx * invc;
    gs[2 * t + 1] = sy * invc;
  }
  __syncthreads();
  if (t < NCLS) {
    float acc = bfc[t];
    #pragma unroll 8
    for (int cc = 0; cc < CH; ++cc)
      acc = fmaf(gs[cc], Wfc[cc * NCLS + t], acc);
    outp[g * NCLS + t] = acc;
  }
}

// ---------------------------------------------------------------------------
extern "C" void kernel_launch(void* const* d_in, const int* in_sizes, int n_in,
                              void* d_out, int out_size, void* d_ws, size_t ws_size,
                              hipStream_t stream) {
  const float* x    = (const float*)d_in[0];
  const int*   ei   = (const int*)d_in[1];
  const int*   batch= (const int*)d_in[2];
  const float* W1   = (const float*)d_in[3];
  const float* b1   = (const float*)d_in[4];
  const float* W2   = (const float*)d_in[5];
  const float* b2   = (const float*)d_in[6];
  const float* Wfc  = (const float*)d_in[7];
  const float* bfc  = (const float*)d_in[8];
  float* outp = (float*)d_out;

  const int N = in_sizes[0] / CH;       // 100000
  const int E = in_sizes[1] / 2;        // 3200000
  const int* src = ei;
  const int* dst = ei + E;
  const int NBUCK = (N + BW - 1) >> BSHIFT;   // 391
  int CAP = (E / NBUCK) + (E / NBUCK) / 8 + 1280;
  CAP = (CAP + 3) & ~3;                       // keep per-bucket base 4-aligned

  // Workspace carve (256B aligned).
  char* w = (char*)d_ws;
  size_t o = 0;
  auto carve = [&](size_t bytes) -> void* {
    o = (o + 255) & ~(size_t)255;
    void* p = w + o;
    o += bytes;
    return p;
  };
  int*      offs   = (int*)     carve((size_t)N * 4);
  int*      oendb  = (int*)     carve((size_t)N * 4);
  int*      gcur   = (int*)     carve(MAXB * 4);                 // zeroed
  int*      csr    = (int*)     carve((size_t)NBUCK * CAP * 4);
  float*    dinv   = (float*)   carve((size_t)N * 4);
  _Float16* WhT1   = (_Float16*)carve((size_t)CH * CH * 2);
  _Float16* WhT2   = (_Float16*)carve((size_t)CH * CH * 2);
  unsigned char* xsbuf = (unsigned char*)carve((size_t)(N + 1) * CH); // fp8 + zero row
  __half*   hbuf   = (__half*)  carve((size_t)N * CH * 2);            // fp16 h
  (void)ws_size;

  // ebuf (packed edges, gapped) aliases hbuf: NBUCK*CAP*4 ~ 16.4MB <= 25.6MB
  int* ebuf = (int*)hbuf;

  (void)hipMemsetAsync(gcur, 0, MAXB * 4, stream);

  const int GBW = 1024;                 // waveGemm blocks (4/CU)
  int AB = (N + 7) / 8;
  if (AB > 2048) AB = 2048;

  k_scatter<<<(E + 8191) / 8192, 1024, 0, stream>>>(
      src, dst, gcur, ebuf, E, CAP, (int*)(xsbuf + (size_t)N * CH));
  k_build<<<NBUCK, 1024, 0, stream>>>(ebuf, gcur, offs, oendb, dinv, csr,
                                      N, CAP, W1, W2, WhT1, WhT2);

  // Layer 1: xs = fp8((x@W1)*dinv*64) ; h = fp16(relu(agg(xs)*dinv/64 + b1))
  k_gemm_f32<<<GBW, 256, 0, stream>>>(x, WhT1, dinv, xsbuf, N);
  k_agg<<<AB, 256, 0, stream>>>((const unsigned int*)xsbuf, csr, offs, oendb,
                                dinv, b1, hbuf, N);
  // Layer 2
  k_gemm_f16<<<GBW, 256, 0, stream>>>((const _Float16*)hbuf, WhT2, dinv, xsbuf, N);
  k_agg<<<AB, 256, 0, stream>>>((const unsigned int*)xsbuf, csr, offs, oendb,
                                dinv, b2, hbuf, N);

  // Fused pool + FC
  k_poolfc<<<NGRAPH, 256, 0, stream>>>(hbuf, batch, Wfc, bfc, outp, N);
  (void)out_size; (void)n_in;
}